// Round 3
// baseline (424.560 us; speedup 1.0000x reference)
//
#include <hip/hip_runtime.h>
#include <hip/hip_bf16.h>

#define NT   8
#define INF  128
#define OUTF 64
#define BR   256    // rows per block (local binning granularity)

typedef __attribute__((ext_vector_type(8))) short short8;   // 8 bf16 (4 VGPRs)
typedef __attribute__((ext_vector_type(4))) float f32x4;

__device__ __forceinline__ short f2bf(float f) {
  __hip_bfloat16 h = __float2bfloat16(f);
  return __builtin_bit_cast(short, h);
}

// ---------------------------------------------------------------------------
// wbf[128 * 512] shorts (128 KB) in d_ws: W as bf16 in MFMA B-fragment order.
//   frag fi = (t*4 + s)*4 + nb, lane(q,c), j:
//   wbf[fi*512 + lane*8 + j] = bf16( W[t][s*32 + q*8 + j][nb*16 + c] )
// (verified in earlier rounds)
// ---------------------------------------------------------------------------
__global__ void hl_wconv(const float* __restrict__ W, short* __restrict__ wbf) {
  const int tid   = blockIdx.x * blockDim.x + threadIdx.x;  // 0..8191
  const int combo = tid >> 6;                               // 0..127 == fi
  const int lane  = tid & 63;
  const int t = combo >> 4, s = (combo >> 2) & 3, nb = combo & 3;
  const int q = lane >> 4, c = lane & 15;
  const float* Wt = W + t * INF * OUTF;
  short8 v;
  #pragma unroll
  for (int j = 0; j < 8; ++j)
    v[j] = f2bf(Wt[(s * 32 + q * 8 + j) * OUTF + nb * 16 + c]);
  *(short8*)(wbf + (size_t)tid * 8) = v;
}

// ---------------------------------------------------------------------------
// No-stage locally-binned GEMM. One block = 256 consecutive rows:
//   1. bin rows by type in-block (LDS atomic rank -> lorder[], ~1 KB LDS)
//   2. one MFMA tile per (type, 16-row chunk). A-fragments gather DIRECTLY
//      from global x by lorder: for fixed s, lanes q=0..3 of a c read
//      consecutive 32-B chunks = one full 128-B line of row lorder[c] ->
//      full-line, zero-overfetch requests scattered in a 128-KB window.
//      All 8 A-loads per tile independent + unrolled (8 KB/wave in flight).
//   3. B streamed from L2-hot wbf (128 KB); bias + store into the block's
//      64-KB out window.
// E[tiles] ~= 20 per 256 rows (vs 16 ideal). No x LDS round-trip, no stage
// barrier, ~1 KB LDS -> occupancy limited only by VGPRs (~20 waves/CU).
// Fragment mappings (verified in prior rounds):
//   A: m = lane&15, k = q*8 + j (per s-step of 32)
//   B: k = s*32 + q*8 + j, n = nb*16 + c
//   C/D: n = lane&15, m = q*4 + reg
// ---------------------------------------------------------------------------
__global__ __launch_bounds__(256, 4) void hl_nb(
    const float* __restrict__ x, const int* __restrict__ nty,
    const short* __restrict__ wbf, const float* __restrict__ b,
    float* __restrict__ out, int N) {
  __shared__ int lcnt[NT], cbase[NT];
  __shared__ short lorder[BR];
  __shared__ int descs[NT + BR / 16];     // <= 8 partial + 16 full
  __shared__ int ndesc;

  const int tid   = threadIdx.x;
  const int base  = blockIdx.x * BR;
  const int nrows = min(BR, N - base);

  // ---- bin: per-type rank (order within type irrelevant) ----
  int myty = 0;
  if (tid < nrows) myty = nty[base + tid];      // issue load early
  if (tid < NT) lcnt[tid] = 0;
  __syncthreads();
  int myrank = 0;
  if (tid < nrows) myrank = atomicAdd(&lcnt[myty], 1);
  __syncthreads();
  if (tid < NT) {                               // tiny exclusive scan
    int o = 0;
    #pragma unroll
    for (int t = 0; t < NT; ++t) o += (t < tid) ? lcnt[t] : 0;
    cbase[tid] = o;
  }
  if (tid == 0) {                               // descriptor build (serial, tiny)
    int nd = 0, o = 0;
    for (int t = 0; t < NT; ++t) {
      const int cn = lcnt[t];
      for (int j = 0; j < cn; j += 16)
        descs[nd++] = t | (min(16, cn - j) << 3) | ((o + j) << 8);
      o += cn;
    }
    ndesc = nd;
  }
  __syncthreads();
  if (tid < nrows) lorder[cbase[myty] + myrank] = (short)tid;
  __syncthreads();

  // ---- tile loop: waves round-robin over descriptors ----
  const int wave = tid >> 6, lane = tid & 63;
  const int q = lane >> 4, c = lane & 15;
  const int nd = ndesc;
  const short* wp = wbf + lane * 8;             // + fi*512 per fragment

  for (int i = wave; i < nd; i += 4) {
    const int d = descs[i];
    const int t = d & 7, valid = (d >> 3) & 31, loff = d >> 8;

    // A fragments: output row m = c, row index gathered via lorder
    const int am   = c < valid ? c : valid - 1; // dup last row for pad lanes
    const int lrow = lorder[loff + am];
    const float* xr = x + (size_t)(base + lrow) * INF;
    short8 A[4];
    #pragma unroll
    for (int s = 0; s < 4; ++s) {
      f32x4 v0 = *(const f32x4*)(xr + s * 32 + q * 8);
      f32x4 v1 = *(const f32x4*)(xr + s * 32 + q * 8 + 4);
      short8 a;
      #pragma unroll
      for (int j = 0; j < 4; ++j) { a[j] = f2bf(v0[j]); a[j + 4] = f2bf(v1[j]); }
      A[s] = a;
    }

    f32x4 acc[4];
    #pragma unroll
    for (int nb = 0; nb < 4; ++nb) acc[nb] = (f32x4){0, 0, 0, 0};

    #pragma unroll
    for (int s = 0; s < 4; ++s) {
      #pragma unroll
      for (int nb = 0; nb < 4; ++nb) {
        short8 B = *(const short8*)(wp + (size_t)((t * 4 + s) * 4 + nb) * 512);
        acc[nb] = __builtin_amdgcn_mfma_f32_16x16x32_bf16(A[s], B, acc[nb], 0, 0, 0);
      }
    }

    // epilogue: D row m = q*4+r, col = c + nb*16; single-type bias
    float bv[4];
    #pragma unroll
    for (int nb = 0; nb < 4; ++nb) bv[nb] = b[t * OUTF + nb * 16 + c];
    #pragma unroll
    for (int r = 0; r < 4; ++r) {
      const int m = q * 4 + r;
      if (m < valid) {
        const int grow = base + lorder[loff + m];
        float* orow = out + (size_t)grow * OUTF + c;
        #pragma unroll
        for (int nb = 0; nb < 4; ++nb)
          orow[nb * 16] = acc[nb][r] + bv[nb];
      }
    }
  }
}

extern "C" void kernel_launch(void* const* d_in, const int* in_sizes, int n_in,
                              void* d_out, int out_size, void* d_ws, size_t ws_size,
                              hipStream_t stream) {
  const float* x  = (const float*)d_in[0];
  const int*   nt = (const int*)d_in[1];
  const float* W  = (const float*)d_in[2];
  const float* b  = (const float*)d_in[3];
  float* out = (float*)d_out;
  const int N = in_sizes[1];
  short* wbf = (short*)d_ws;              // 128 KB (ws >= 128 KB, proven)

  hl_wconv<<<32, 256, 0, stream>>>(W, wbf);
  const int gb = (N + BR - 1) / BR;
  hl_nb<<<gb, 256, 0, stream>>>(x, nt, wbf, b, out, N);
}

// Round 4
// 393.446 us; speedup vs baseline: 1.0791x; 1.0791x over previous
//
#include <hip/hip_runtime.h>
#include <hip/hip_bf16.h>

#define NT   8
#define INF  128
#define OUTF 64
#define BR   128    // rows per block (local binning granularity)

typedef __attribute__((ext_vector_type(8))) short short8;   // 8 bf16 (4 VGPRs)
typedef __attribute__((ext_vector_type(4))) short short4v;  // 4 bf16 (2 VGPRs)
typedef __attribute__((ext_vector_type(4))) float f32x4;

__device__ __forceinline__ short f2bf(float f) {
  __hip_bfloat16 h = __float2bfloat16(f);
  return __builtin_bit_cast(short, h);
}

// ---------------------------------------------------------------------------
// wbf[128 * 512] shorts (128 KB) in d_ws: W as bf16 in MFMA B-fragment order.
//   frag fi = (t*4 + s)*4 + nb, lane(q,c), j:
//   wbf[fi*512 + lane*8 + j] = bf16( W[t][s*32 + q*8 + j][nb*16 + c] )
// (verified in earlier rounds)
// ---------------------------------------------------------------------------
__global__ void hl_wconv(const float* __restrict__ W, short* __restrict__ wbf) {
  const int tid   = blockIdx.x * blockDim.x + threadIdx.x;  // 0..8191
  const int combo = tid >> 6;                               // 0..127 == fi
  const int lane  = tid & 63;
  const int t = combo >> 4, s = (combo >> 2) & 3, nb = combo & 3;
  const int q = lane >> 4, c = lane & 15;
  const float* Wt = W + t * INF * OUTF;
  short8 v;
  #pragma unroll
  for (int j = 0; j < 8; ++j)
    v[j] = f2bf(Wt[(s * 32 + q * 8 + j) * OUTF + nb * 16 + c]);
  *(short8*)(wbf + (size_t)tid * 8) = v;
}

// ---------------------------------------------------------------------------
// Staged + locally-binned GEMM, MLP-pipelined. One block = 128 rows:
//   stage x -> LDS bf16 (16B-chunk XOR swizzle) as TWO fully-unrolled batches
//   of 8 independent f32x4 loads per thread (8 KB/wave in flight); binning
//   (LDS atomic rank) overlaps the load shadows; 3 barriers total; serial
//   descriptor build overlaps batch-B LDS writes. Compute: one MFMA tile per
//   (type, 16-row chunk); per tile ALL 16 B-frag L2 loads + 4 A ds_reads
//   issued up front, then 16 MFMAs, then bias + stores.
// Fragment mappings (verified in prior rounds):
//   A: m = lane&15, k = q*8 + j (per s-step of 32)
//   B: k = s*32 + q*8 + j, n = nb*16 + c
//   C/D: n = lane&15, m = q*4 + reg
// ---------------------------------------------------------------------------
__global__ __launch_bounds__(256, 4) void hl_sb(
    const float* __restrict__ x, const int* __restrict__ nty,
    const short* __restrict__ wbf, const float* __restrict__ b,
    float* __restrict__ out, int N) {
  __shared__ short xs[BR * 128];          // 32 KB swizzled bf16 tile
  __shared__ int lcnt[NT];
  __shared__ short lorder[BR];
  __shared__ int descs[NT + BR / 16];     // <= 15 used
  __shared__ int ndesc;

  const int tid   = threadIdx.x;
  const int base  = blockIdx.x * BR;
  const int nrows = min(BR, N - base);

  if (tid < NT) lcnt[tid] = 0;
  int myty = 0;
  if (tid < nrows) myty = nty[base + tid];

  // ---- stage batch A: 8 independent f32x4 loads (rows 0..63) ----
  f32x4 va[8];
  #pragma unroll
  for (int k = 0; k < 8; ++k) {
    const int f4 = tid + k * 256;
    int row = f4 >> 5;
    if (row >= nrows) row = nrows - 1;    // tail clamp (source stays in-bounds)
    va[k] = *(const f32x4*)(x + (size_t)(base + row) * INF + (f4 & 31) * 4);
  }
  __syncthreads();                        // lcnt zeroed
  int myrank = 0;
  if (tid < nrows) myrank = atomicAdd(&lcnt[myty], 1);

  // write batch A (waits its loads), swizzled 8B chunks
  #pragma unroll
  for (int k = 0; k < 8; ++k) {
    const int f4 = tid + k * 256;
    const int row = f4 >> 5, q4 = f4 & 31;
    short4v s4;
    s4[0] = f2bf(va[k][0]); s4[1] = f2bf(va[k][1]);
    s4[2] = f2bf(va[k][2]); s4[3] = f2bf(va[k][3]);
    *(short4v*)((char*)xs + row * 256 + ((q4 * 8) ^ ((row & 7) << 4))) = s4;
  }

  // ---- stage batch B: 8 independent loads (rows 64..127), issued early ----
  f32x4 vb[8];
  #pragma unroll
  for (int k = 0; k < 8; ++k) {
    const int f4 = tid + (k + 8) * 256;
    int row = f4 >> 5;
    if (row >= nrows) row = nrows - 1;
    vb[k] = *(const f32x4*)(x + (size_t)(base + row) * INF + (f4 & 31) * 4);
  }
  __syncthreads();                        // rank atomics done, lcnt final

  // per-thread cbase (no cross-thread write dependency) -> lorder
  if (tid < nrows) {
    int mycb = 0;
    #pragma unroll
    for (int t = 0; t < NT; ++t) mycb += (t < myty) ? lcnt[t] : 0;
    lorder[mycb + myrank] = (short)tid;
  }
  if (tid == 0) {                         // tiny serial desc build (overlaps B writes)
    int nd = 0, o = 0;
    for (int t = 0; t < NT; ++t) {
      const int cn = lcnt[t];
      for (int j = 0; j < cn; j += 16)
        descs[nd++] = t | (min(16, cn - j) << 3) | ((o + j) << 8);
      o += cn;
    }
    ndesc = nd;
  }

  // write batch B (waits its loads)
  #pragma unroll
  for (int k = 0; k < 8; ++k) {
    const int f4 = tid + (k + 8) * 256;
    const int row = f4 >> 5, q4 = f4 & 31;
    short4v s4;
    s4[0] = f2bf(vb[k][0]); s4[1] = f2bf(vb[k][1]);
    s4[2] = f2bf(vb[k][2]); s4[3] = f2bf(vb[k][3]);
    *(short4v*)((char*)xs + row * 256 + ((q4 * 8) ^ ((row & 7) << 4))) = s4;
  }
  __syncthreads();                        // xs + lorder + descs visible

  // ---- tile loop: waves round-robin over descriptors ----
  const int wave = tid >> 6, lane = tid & 63;
  const int q = lane >> 4, c = lane & 15;
  const int nd = ndesc;
  const short* wp = wbf + lane * 8;       // + fi*512 per fragment

  for (int i = wave; i < nd; i += 4) {
    const int d = descs[i];
    const int t = d & 7, valid = (d >> 3) & 31, loff = d >> 8;

    // issue ALL memory for this tile up front (max MLP, one wait at MFMA)
    short8 B[4][4];                       // 16 x 16B L2 loads
    #pragma unroll
    for (int s = 0; s < 4; ++s)
      #pragma unroll
      for (int nb = 0; nb < 4; ++nb)
        B[s][nb] = *(const short8*)(wp + (size_t)((t * 4 + s) * 4 + nb) * 512);

    const int am   = c < valid ? c : valid - 1;   // dup last row for pad lanes
    const int lrow = lorder[loff + am];
    const char* arow = (const char*)xs + lrow * 256;
    const int sw = (lrow & 7) << 4;
    short8 A[4];
    #pragma unroll
    for (int s = 0; s < 4; ++s)
      A[s] = *(const short8*)(arow + ((s * 64 + q * 16) ^ sw));

    f32x4 acc[4];
    #pragma unroll
    for (int nb = 0; nb < 4; ++nb) acc[nb] = (f32x4){0, 0, 0, 0};

    #pragma unroll
    for (int s = 0; s < 4; ++s)
      #pragma unroll
      for (int nb = 0; nb < 4; ++nb)
        acc[nb] = __builtin_amdgcn_mfma_f32_16x16x32_bf16(A[s], B[s][nb], acc[nb], 0, 0, 0);

    // epilogue: D row m = q*4+r, col = c + nb*16; single-type bias
    float bv[4];
    #pragma unroll
    for (int nb = 0; nb < 4; ++nb) bv[nb] = b[t * OUTF + nb * 16 + c];
    #pragma unroll
    for (int r = 0; r < 4; ++r) {
      const int m = q * 4 + r;
      if (m < valid) {
        const int grow = base + lorder[loff + m];
        float* orow = out + (size_t)grow * OUTF + c;
        #pragma unroll
        for (int nb = 0; nb < 4; ++nb)
          orow[nb * 16] = acc[nb][r] + bv[nb];
      }
    }
  }
}

extern "C" void kernel_launch(void* const* d_in, const int* in_sizes, int n_in,
                              void* d_out, int out_size, void* d_ws, size_t ws_size,
                              hipStream_t stream) {
  const float* x  = (const float*)d_in[0];
  const int*   nt = (const int*)d_in[1];
  const float* W  = (const float*)d_in[2];
  const float* b  = (const float*)d_in[3];
  float* out = (float*)d_out;
  const int N = in_sizes[1];
  short* wbf = (short*)d_ws;              // 128 KB (ws >= 128 KB, proven)

  hl_wconv<<<32, 256, 0, stream>>>(W, wbf);
  const int gb = (N + BR - 1) / BR;
  hl_sb<<<gb, 256, 0, stream>>>(x, nt, wbf, b, out, N);
}